// Round 2
// baseline (217.249 us; speedup 1.0000x reference)
//
#include <hip/hip_runtime.h>

// Dice loss (hard, exclude background=class 0), B=2, C=8, S=128^3.
// pred: (B, C, 128,128,128) fp32 ; ref: (B, 1, 128,128,128) int32 ; out: scalar fp32.

#define S_VOX (128 * 128 * 128)   // 2,097,152 voxels per (b, c) slice
#define S4    (S_VOX / 4)         // 524,288 float4 groups per slice
#define NC    8                   // channels
#define NFG   7                   // foreground classes (1..7)
#define NT    262144              // threads per batch = grid.x(1024) * block(256)
#define NITER (S4 / NT)           // = 2, compile-time -> fully unrolled

// ws layout (int): per batch b: [b*21 + 0..6]=inter, [7..13]=psum(pred), [14..20]=rsum(ref)
#define WS_INTS (2 * 3 * NFG)

// Per-component argmax + per-WAVE ballot counting.
// __ballot is wave-uniform -> the 21 accumulators live in SGPRs and the
// popcount/accumulate work runs on the SALU pipe (co-issues with VALU).
#define PROC_COMP(C)                                                     \
    {                                                                    \
        float bv = a0.C; int bi = 0;                                     \
        if (a1.C > bv) { bv = a1.C; bi = 1; }                            \
        if (a2.C > bv) { bv = a2.C; bi = 2; }                            \
        if (a3.C > bv) { bv = a3.C; bi = 3; }                            \
        if (a4.C > bv) { bv = a4.C; bi = 4; }                            \
        if (a5.C > bv) { bv = a5.C; bi = 5; }                            \
        if (a6.C > bv) { bv = a6.C; bi = 6; }                            \
        if (a7.C > bv) { bv = a7.C; bi = 7; }                            \
        const int rr = r.C;                                              \
        _Pragma("unroll")                                                \
        for (int c = 1; c < NC; ++c) {                                   \
            const unsigned long long mp = __ballot(bi == c);             \
            const unsigned long long mr = __ballot(rr == c);             \
            cp[c - 1] += (int)__popcll(mp);                              \
            cr[c - 1] += (int)__popcll(mr);                              \
            ci[c - 1] += (int)__popcll(mp & mr);                         \
        }                                                                \
    }

__global__ __launch_bounds__(256) void dice_count_kernel(
    const float4* __restrict__ pred4, const int4* __restrict__ ref4,
    int* __restrict__ ws)
{
    const int b = blockIdx.y;
    // Wave-uniform counters (SGPRs via ballot/popc uniformity).
    int ci[NFG], cp[NFG], cr[NFG];
#pragma unroll
    for (int k = 0; k < NFG; ++k) { ci[k] = 0; cp[k] = 0; cr[k] = 0; }

    const int tid = blockIdx.x * 256 + threadIdx.x;   // 0..NT-1 within batch
    // base offsets in float4 / int4 units
    const long long predBase = (long long)b * NC * S4;
    const long long refBase  = (long long)b * S4;

    // Compile-time trip count (NITER==2): fully unrolled so the compiler can
    // cluster all 18 global_load_dwordx4 before the dependent VALU/SALU work.
    // No tail: NT*NITER == S4 exactly -> every lane always active (ballot-safe).
#pragma unroll
    for (int it = 0; it < NITER; ++it) {
        const int g = tid + it * NT;
        const float4 a0 = pred4[predBase + (long long)0 * S4 + g];
        const float4 a1 = pred4[predBase + (long long)1 * S4 + g];
        const float4 a2 = pred4[predBase + (long long)2 * S4 + g];
        const float4 a3 = pred4[predBase + (long long)3 * S4 + g];
        const float4 a4 = pred4[predBase + (long long)4 * S4 + g];
        const float4 a5 = pred4[predBase + (long long)5 * S4 + g];
        const float4 a6 = pred4[predBase + (long long)6 * S4 + g];
        const float4 a7 = pred4[predBase + (long long)7 * S4 + g];
        const int4   r  = ref4[refBase + g];
        PROC_COMP(x)
        PROC_COMP(y)
        PROC_COMP(z)
        PROC_COMP(w)
    }

    // Counters are already per-wave totals. Reduce the block's waves via LDS.
    __shared__ int sh[3 * NFG];
    if (threadIdx.x < 3 * NFG) sh[threadIdx.x] = 0;
    __syncthreads();

    const int lane = threadIdx.x & 63;
    if (lane == 0) {
#pragma unroll
        for (int k = 0; k < NFG; ++k) {
            atomicAdd(&sh[k], ci[k]);
            atomicAdd(&sh[NFG + k], cp[k]);
            atomicAdd(&sh[2 * NFG + k], cr[k]);
        }
    }
    __syncthreads();

    if (threadIdx.x < 3 * NFG) {
        atomicAdd(&ws[b * (3 * NFG) + threadIdx.x], sh[threadIdx.x]);
    }
}

__global__ void dice_finalize_kernel(const int* __restrict__ ws,
                                     float* __restrict__ out)
{
    if (blockIdx.x == 0 && threadIdx.x == 0) {
        float total = 0.0f;
#pragma unroll
        for (int b = 0; b < 2; ++b) {
            const int* w = ws + b * (3 * NFG);
            float sumd = 0.0f, sumw = 0.0f;
#pragma unroll
            for (int k = 0; k < NFG; ++k) {
                const int I = w[k];
                const int P = w[NFG + k];
                const int R = w[2 * NFG + k];
                if (R > 0) {
                    sumw += 1.0f;
                    sumd += 2.0f * (float)I / (float)(P + R);
                }
            }
            total += sumd / sumw;   // matches reference (NaN if no ref classes)
        }
        out[0] = 0.5f * total;
    }
}

extern "C" void kernel_launch(void* const* d_in, const int* in_sizes, int n_in,
                              void* d_out, int out_size, void* d_ws, size_t ws_size,
                              hipStream_t stream) {
    const float* pred = (const float*)d_in[0];
    const int*   ref  = (const int*)d_in[1];
    float*       out  = (float*)d_out;
    int*         ws   = (int*)d_ws;

    // ws is re-poisoned to 0xAA before every timed launch -> zero it each call.
    hipMemsetAsync(ws, 0, WS_INTS * sizeof(int), stream);

    // 2048 blocks x 256 threads. NT (=grid.x*block) is baked into the kernel
    // as a compile-time constant so the 2-trip loop fully unrolls.
    dim3 grid(1024, 2, 1);
    dim3 block(256, 1, 1);
    dice_count_kernel<<<grid, block, 0, stream>>>(
        (const float4*)pred, (const int4*)ref, ws);
    dice_finalize_kernel<<<1, 64, 0, stream>>>(ws, out);
}

// Round 3
// 211.064 us; speedup vs baseline: 1.0293x; 1.0293x over previous
//
#include <hip/hip_runtime.h>

// Dice loss (hard, exclude background=class 0), B=2, C=8, S=128^3.
// pred: (B, C, 128,128,128) fp32 ; ref: (B, 1, 128,128,128) int32 ; out: scalar fp32.
//
// e2e budget (measured): harness ws-poison fills ~157 us (untouchable) +
// count kernel ~25 us (memory-bound: 151 MB mandatory read) + dispatch overhead.
// This version removes the ws memset dispatch (3 -> 2 dispatches) by having each
// block plain-store its partial counters to a private slot (no zero-init needed;
// kernel-boundary release/acquire makes stores visible to the finalize dispatch).

#define S_VOX (128 * 128 * 128)   // 2,097,152 voxels per (b, c) slice
#define S4    (S_VOX / 4)         // 524,288 float4 groups per slice
#define NC    8                   // channels
#define NFG   7                   // foreground classes (1..7)
#define NCNT  (3 * NFG)           // 21 counters per block: inter, psum, rsum

#define GX    256                 // blocks per batch
#define NT    (GX * 256)          // 65536 threads per batch
#define NITER (S4 / NT)           // = 8, compile-time

#define NSLOT (2 * GX)            // 512 partial slots (b*GX + bx)
// ws layout (j-major for coalesced finalize reads): ws[j * NSLOT + slot], j in [0,21)

// Per-component argmax + per-WAVE ballot counting.
// __ballot is wave-uniform -> the 21 accumulators live in SGPRs; popcount work
// runs on the SALU pipe (co-issues with VALU). No tail: every lane always active.
#define PROC_COMP(C)                                                     \
    {                                                                    \
        float bv = a0.C; int bi = 0;                                     \
        if (a1.C > bv) { bv = a1.C; bi = 1; }                            \
        if (a2.C > bv) { bv = a2.C; bi = 2; }                            \
        if (a3.C > bv) { bv = a3.C; bi = 3; }                            \
        if (a4.C > bv) { bv = a4.C; bi = 4; }                            \
        if (a5.C > bv) { bv = a5.C; bi = 5; }                            \
        if (a6.C > bv) { bv = a6.C; bi = 6; }                            \
        if (a7.C > bv) { bv = a7.C; bi = 7; }                            \
        const int rr = r.C;                                              \
        _Pragma("unroll")                                                \
        for (int c = 1; c < NC; ++c) {                                   \
            const unsigned long long mp = __ballot(bi == c);             \
            const unsigned long long mr = __ballot(rr == c);             \
            cp[c - 1] += (int)__popcll(mp);                              \
            cr[c - 1] += (int)__popcll(mr);                              \
            ci[c - 1] += (int)__popcll(mp & mr);                         \
        }                                                                \
    }

__global__ __launch_bounds__(256) void dice_count_kernel(
    const float4* __restrict__ pred4, const int4* __restrict__ ref4,
    int* __restrict__ ws)
{
    const int b = blockIdx.y;
    int ci[NFG], cp[NFG], cr[NFG];
#pragma unroll
    for (int k = 0; k < NFG; ++k) { ci[k] = 0; cp[k] = 0; cr[k] = 0; }

    const int tid = blockIdx.x * 256 + threadIdx.x;   // 0..NT-1 within batch
    const long long predBase = (long long)b * NC * S4;
    const long long refBase  = (long long)b * S4;

    // 8 compile-time iterations, unroll 2 -> 18 loads in flight per thread,
    // VGPR stays moderate. NT*NITER == S4 exactly (ballot-safe, no tail).
#pragma unroll 2
    for (int it = 0; it < NITER; ++it) {
        const int g = tid + it * NT;
        const float4 a0 = pred4[predBase + (long long)0 * S4 + g];
        const float4 a1 = pred4[predBase + (long long)1 * S4 + g];
        const float4 a2 = pred4[predBase + (long long)2 * S4 + g];
        const float4 a3 = pred4[predBase + (long long)3 * S4 + g];
        const float4 a4 = pred4[predBase + (long long)4 * S4 + g];
        const float4 a5 = pred4[predBase + (long long)5 * S4 + g];
        const float4 a6 = pred4[predBase + (long long)6 * S4 + g];
        const float4 a7 = pred4[predBase + (long long)7 * S4 + g];
        const int4   r  = ref4[refBase + g];
        PROC_COMP(x)
        PROC_COMP(y)
        PROC_COMP(z)
        PROC_COMP(w)
    }

    // Per-wave totals -> block totals via LDS.
    __shared__ int sh[NCNT];
    if (threadIdx.x < NCNT) sh[threadIdx.x] = 0;
    __syncthreads();

    if ((threadIdx.x & 63) == 0) {
#pragma unroll
        for (int k = 0; k < NFG; ++k) {
            atomicAdd(&sh[k], ci[k]);
            atomicAdd(&sh[NFG + k], cp[k]);
            atomicAdd(&sh[2 * NFG + k], cr[k]);
        }
    }
    __syncthreads();

    // Plain store to this block's private slot -- no init, no global atomics.
    const int slot = b * GX + blockIdx.x;
    if (threadIdx.x < NCNT) {
        ws[threadIdx.x * NSLOT + slot] = sh[threadIdx.x];
    }
}

__global__ void dice_finalize_kernel(const int* __restrict__ ws,
                                     float* __restrict__ out)
{
    // 2*NCNT = 42 (batch, counter) combos; each lane sums its GX=256 slots
    // (consecutive addresses -> sequential L2-friendly reads).
    __shared__ int tot[2 * NCNT];
    const int t = threadIdx.x;
    if (t < 2 * NCNT) {
        const int b2 = t / NCNT;
        const int jj = t % NCNT;
        const int* base = ws + jj * NSLOT + b2 * GX;
        int s = 0;
#pragma unroll 8
        for (int i = 0; i < GX; ++i) s += base[i];
        tot[t] = s;
    }
    __syncthreads();

    if (t == 0) {
        float total = 0.0f;
#pragma unroll
        for (int b2 = 0; b2 < 2; ++b2) {
            const int* w = tot + b2 * NCNT;
            float sumd = 0.0f, sumw = 0.0f;
#pragma unroll
            for (int k = 0; k < NFG; ++k) {
                const int I = w[k];
                const int P = w[NFG + k];
                const int R = w[2 * NFG + k];
                if (R > 0) {
                    sumw += 1.0f;
                    sumd += 2.0f * (float)I / (float)(P + R);
                }
            }
            total += sumd / sumw;   // matches reference (NaN if no ref classes)
        }
        out[0] = 0.5f * total;
    }
}

extern "C" void kernel_launch(void* const* d_in, const int* in_sizes, int n_in,
                              void* d_out, int out_size, void* d_ws, size_t ws_size,
                              hipStream_t stream) {
    const float* pred = (const float*)d_in[0];
    const int*   ref  = (const int*)d_in[1];
    float*       out  = (float*)d_out;
    int*         ws   = (int*)d_ws;

    // No ws memset needed: every ws word we read is plain-stored by
    // dice_count_kernel in the same timed iteration (slots are write-then-read).
    dim3 grid(GX, 2, 1);
    dim3 block(256, 1, 1);
    dice_count_kernel<<<grid, block, 0, stream>>>(
        (const float4*)pred, (const int4*)ref, ws);
    dice_finalize_kernel<<<1, 64, 0, stream>>>(ws, out);
}